// Round 1
// baseline (1989.727 us; speedup 1.0000x reference)
//
#include <hip/hip_runtime.h>
#include <stdint.h>

#define Q    2048
#define NB   40000
#define NK   2048
#define ND   512
#define SCORE_SIZE (Q * NB)   // 81,920,000

typedef __bf16 bf16;
typedef bf16  bf16x8 __attribute__((ext_vector_type(8)));
typedef float f32x4  __attribute__((ext_vector_type(4)));

__device__ __forceinline__ unsigned short f2bf_rne(float f) {
    unsigned int u = __float_as_uint(f);
    u += 0x7FFFu + ((u >> 16) & 1u);
    return (unsigned short)(u >> 16);
}

// ---------------------------------------------------------------- c2 = ||cb_k||^2
__global__ __launch_bounds__(256) void c2_kernel(const float* __restrict__ cb,
                                                 float* __restrict__ c2) {
    int wave = threadIdx.x >> 6, lane = threadIdx.x & 63;
    int row  = blockIdx.x * 4 + wave;          // grid = NK/4 = 512
    const float4* p = (const float4*)(cb + (size_t)row * ND);
    float4 a = p[lane];
    float4 b = p[lane + 64];
    float s = a.x*a.x + a.y*a.y + a.z*a.z + a.w*a.w
            + b.x*b.x + b.y*b.y + b.z*b.z + b.w*b.w;
    #pragma unroll
    for (int off = 32; off; off >>= 1) s += __shfl_down(s, off);
    if (lane == 0) c2[row] = s;
}

// ------------------------------------------- fp32 distance GEMM + per-tile argmin
// block: 256 threads, tile 128 entities x 128 codes, full D loop.
// grid: (ceil(NB/128)=313, NK/128=16). partial[kt*NB + b] = (minval, idx bits)
#define DPAD 132
__global__ __launch_bounds__(256) void dist_argmin_kernel(
        const float* __restrict__ ent, const float* __restrict__ cb,
        const float* __restrict__ c2g, float2* __restrict__ partial) {
    __shared__ float Es[32 * DPAD];   // [d][entity]  transposed stage
    __shared__ float Cs[32 * DPAD];   // [d][code]
    int tid = threadIdx.x;
    int b0 = blockIdx.x * 128;
    int k0 = blockIdx.y * 128;
    int tx = tid & 15;      // code group   (8 codes)
    int ty = tid >> 4;      // entity group (8 entities)

    float acc[8][8] = {};

    for (int dc = 0; dc < ND; dc += 32) {
        __syncthreads();
        #pragma unroll
        for (int q = 0; q < 4; ++q) {
            int f4 = q * 256 + tid;            // 0..1023 float4 slots per matrix
            int r  = f4 >> 3;                  // row in tile 0..127
            int cc = f4 & 7;                   // float4 column 0..7
            int br = b0 + r; br = br < NB ? br : NB - 1;
            float4 evv = *(const float4*)(ent + (size_t)br * ND + dc + cc * 4);
            float4 cvv = *(const float4*)(cb  + (size_t)(k0 + r) * ND + dc + cc * 4);
            int col = cc * 4;
            Es[(col + 0) * DPAD + r] = evv.x;
            Es[(col + 1) * DPAD + r] = evv.y;
            Es[(col + 2) * DPAD + r] = evv.z;
            Es[(col + 3) * DPAD + r] = evv.w;
            Cs[(col + 0) * DPAD + r] = cvv.x;
            Cs[(col + 1) * DPAD + r] = cvv.y;
            Cs[(col + 2) * DPAD + r] = cvv.z;
            Cs[(col + 3) * DPAD + r] = cvv.w;
        }
        __syncthreads();
        #pragma unroll 8
        for (int dd = 0; dd < 32; ++dd) {
            float4 e0 = *(const float4*)&Es[dd * DPAD + ty * 8];
            float4 e1 = *(const float4*)&Es[dd * DPAD + ty * 8 + 4];
            float4 q0 = *(const float4*)&Cs[dd * DPAD + tx * 8];
            float4 q1 = *(const float4*)&Cs[dd * DPAD + tx * 8 + 4];
            float ev[8] = {e0.x, e0.y, e0.z, e0.w, e1.x, e1.y, e1.z, e1.w};
            float cv[8] = {q0.x, q0.y, q0.z, q0.w, q1.x, q1.y, q1.z, q1.w};
            #pragma unroll
            for (int i = 0; i < 8; ++i)
                #pragma unroll
                for (int j = 0; j < 8; ++j)
                    acc[i][j] = fmaf(ev[i], cv[j], acc[i][j]);
        }
    }

    float c2v[8];
    #pragma unroll
    for (int j = 0; j < 8; ++j) c2v[j] = c2g[k0 + tx * 8 + j];

    for (int i = 0; i < 8; ++i) {
        int b = b0 + ty * 8 + i;
        float best = c2v[0] - 2.0f * acc[i][0];
        int bidx = k0 + tx * 8;
        #pragma unroll
        for (int j = 1; j < 8; ++j) {
            float v = c2v[j] - 2.0f * acc[i][j];
            if (v < best) { best = v; bidx = k0 + tx * 8 + j; }  // first-index wins
        }
        #pragma unroll
        for (int off = 1; off < 16; off <<= 1) {
            float ov = __shfl_xor(best, off);
            int   oi = __shfl_xor(bidx, off);
            if (ov < best || (ov == best && oi < bidx)) { best = ov; bidx = oi; }
        }
        if (tx == 0 && b < NB)
            partial[(size_t)blockIdx.y * NB + b] = make_float2(best, __int_as_float(bidx));
    }
}

// -------------------------------------------------- reduce 16 K-tile partials
__global__ __launch_bounds__(256) void argmin_reduce_kernel(
        const float2* __restrict__ partial, int* __restrict__ idx_ws,
        float* __restrict__ out_idx) {
    int b = blockIdx.x * 256 + threadIdx.x;
    if (b >= NB) return;
    float2 p0 = partial[b];
    float best = p0.x;
    int bidx = __float_as_int(p0.y);
    #pragma unroll
    for (int t = 1; t < 16; ++t) {
        float2 p = partial[(size_t)t * NB + b];
        int i = __float_as_int(p.y);
        if (p.x < best || (p.x == best && i < bidx)) { best = p.x; bidx = i; }
    }
    idx_ws[b] = bidx;
    out_idx[b] = (float)bidx;
}

// ------------------------------- gather quant (bf16) + vq_loss partial sums
__global__ __launch_bounds__(256) void gather_loss_kernel(
        const float* __restrict__ ent, const float* __restrict__ cb,
        const int* __restrict__ idx_ws, unsigned short* __restrict__ quantb,
        float* __restrict__ acc) {
    int b = blockIdx.x;                 // grid = NB
    int k = idx_ws[b];
    int d = threadIdx.x * 2;
    float2 cv = *(const float2*)(cb  + (size_t)k * ND + d);
    float2 xv = *(const float2*)(ent + (size_t)b * ND + d);
    unsigned int packed = (unsigned int)f2bf_rne(cv.x) | ((unsigned int)f2bf_rne(cv.y) << 16);
    *(unsigned int*)(quantb + (size_t)b * ND + d) = packed;
    float dx = cv.x - xv.x, dy = cv.y - xv.y;
    float s = dx * dx + dy * dy;
    #pragma unroll
    for (int off = 32; off; off >>= 1) s += __shfl_down(s, off);
    __shared__ float wsum[4];
    int lane = threadIdx.x & 63, wave = threadIdx.x >> 6;
    if (lane == 0) wsum[wave] = s;
    __syncthreads();
    if (threadIdx.x == 0) atomicAdd(acc, wsum[0] + wsum[1] + wsum[2] + wsum[3]);
}

__global__ void vq_final_kernel(const float* __restrict__ acc, float* __restrict__ out) {
    out[0] = 1.25f * acc[0] / (float)(NB * ND);
}

// ---------------------------------------------------------- query -> bf16
__global__ __launch_bounds__(256) void qcvt_kernel(const float* __restrict__ qry,
                                                   unsigned short* __restrict__ qb) {
    int i = (blockIdx.x * 256 + threadIdx.x) * 4;   // grid = Q*ND/1024 = 1024
    float4 v = *(const float4*)(qry + i);
    uint2 u;
    u.x = (unsigned int)f2bf_rne(v.x) | ((unsigned int)f2bf_rne(v.y) << 16);
    u.y = (unsigned int)f2bf_rne(v.z) | ((unsigned int)f2bf_rne(v.w) << 16);
    *(uint2*)(qb + i) = u;
}

// --------------------------- score = query @ quant^T, bf16 MFMA 128x128x32 tiles
// A = query_bf16 (Q x ND) row-major; Bt = quant_bf16 (NB x ND) row-major.
// grid: (ceil(NB/128)=313, Q/128=16); 4 waves in 2x2, each 64x64 = 4x4 frags.
__global__ __launch_bounds__(256) void score_kernel(
        const unsigned short* __restrict__ Aq, const unsigned short* __restrict__ Bq,
        float* __restrict__ C) {
    __shared__ unsigned short As[128 * 32];
    __shared__ unsigned short Bs[128 * 32];
    int tid = threadIdx.x;
    int n0 = blockIdx.x * 128;
    int m0 = blockIdx.y * 128;
    int lane = tid & 63, wave = tid >> 6;
    int wm = wave >> 1, wn = wave & 1;
    int lr = lane & 15, quad = lane >> 4;

    f32x4 acc[4][4] = {};

    for (int kt = 0; kt < ND; kt += 32) {
        __syncthreads();
        #pragma unroll
        for (int r = 0; r < 2; ++r) {
            int e = r * 256 + tid;             // 0..511 chunks of 8 bf16
            int row = e >> 2, cc = e & 3;
            uint4 va = *(const uint4*)(Aq + (size_t)(m0 + row) * ND + kt + cc * 8);
            *(uint4*)(As + row * 32 + cc * 8) = va;
            int nr = n0 + row; nr = nr < NB ? nr : NB - 1;
            uint4 vb = *(const uint4*)(Bq + (size_t)nr * ND + kt + cc * 8);
            *(uint4*)(Bs + row * 32 + cc * 8) = vb;
        }
        __syncthreads();
        bf16x8 af[4], bfr[4];
        #pragma unroll
        for (int mi = 0; mi < 4; ++mi)
            af[mi] = *(const bf16x8*)(As + (wm * 64 + mi * 16 + lr) * 32 + quad * 8);
        #pragma unroll
        for (int ni = 0; ni < 4; ++ni)
            bfr[ni] = *(const bf16x8*)(Bs + (wn * 64 + ni * 16 + lr) * 32 + quad * 8);
        #pragma unroll
        for (int mi = 0; mi < 4; ++mi)
            #pragma unroll
            for (int ni = 0; ni < 4; ++ni)
                acc[mi][ni] = __builtin_amdgcn_mfma_f32_16x16x32_bf16(
                    af[mi], bfr[ni], acc[mi][ni], 0, 0, 0);
    }

    // C/D layout (verified m89/m91): col = lane&15, row = (lane>>4)*4 + reg
    #pragma unroll
    for (int mi = 0; mi < 4; ++mi) {
        #pragma unroll
        for (int ni = 0; ni < 4; ++ni) {
            int col = n0 + wn * 64 + ni * 16 + lr;
            if (col < NB) {
                #pragma unroll
                for (int r = 0; r < 4; ++r) {
                    int row = m0 + wm * 64 + mi * 16 + quad * 4 + r;
                    C[(size_t)row * NB + col] = acc[mi][ni][r];
                }
            }
        }
    }
}

extern "C" void kernel_launch(void* const* d_in, const int* in_sizes, int n_in,
                              void* d_out, int out_size, void* d_ws, size_t ws_size,
                              hipStream_t stream) {
    const float* qry = (const float*)d_in[0];   // (2048, 512)
    const float* ent = (const float*)d_in[1];   // (40000, 512)
    const float* cb  = (const float*)d_in[2];   // (2048, 512)
    float* out = (float*)d_out;                 // [score | vq_loss | idx]

    char* ws = (char*)d_ws;
    unsigned short* quantb = (unsigned short*)(ws);               // 40,960,000 B
    unsigned short* qb     = (unsigned short*)(ws + 40960000);    //  2,097,152 B
    float2*         partial= (float2*)(ws + 43057152);            //  5,120,000 B
    int*            idx_ws = (int*)(ws + 48177152);               //    160,000 B
    float*          c2     = (float*)(ws + 48337152);             //      8,192 B
    float*          acc    = (float*)(ws + 48345344);             //          4 B

    hipMemsetAsync(acc, 0, sizeof(float), stream);

    c2_kernel<<<NK / 4, 256, 0, stream>>>(cb, c2);
    dist_argmin_kernel<<<dim3(313, 16), 256, 0, stream>>>(ent, cb, c2, partial);
    argmin_reduce_kernel<<<(NB + 255) / 256, 256, 0, stream>>>(
        partial, idx_ws, out + SCORE_SIZE + 1);
    gather_loss_kernel<<<NB, 256, 0, stream>>>(ent, cb, idx_ws, quantb, acc);
    vq_final_kernel<<<1, 1, 0, stream>>>(acc, out + SCORE_SIZE);
    qcvt_kernel<<<1024, 256, 0, stream>>>(qry, qb);
    score_kernel<<<dim3(313, 16), 256, 0, stream>>>(qb, quantb, out);
}